// Round 13
// baseline (70.093 us; speedup 1.0000x reference)
//
#include <hip/hip_runtime.h>

// Mixture-of-Tastes forward with in-replay operand packing (prefetch-by-
// transformation):
//   zero:     cnt[NB]+ovfMeta = 0
//   cvtU:     [attn_u; taste_u] -> packed fp16, 1KB/user (streaming 41MB read
//             @ ~6-7TB/s; leaves working set L2/L3-resident for main)
//   cvtM:     movie rows -> fp16 (64B/row)
//   scatter:  fixed-cap user buckets (cap=64) + overflow list
//   main:     wave64 = 2 users; per 16-edge tile one mfma_f32_16x16x32_f16.
//             A-frag = ONE half8 load; B-frag = ONE half8 load. Epilogue:
//             xor32 + 4 exps + xor16 (partial-softmax, R12-validated).
// Rationale: R2-R12 showed every main structure lands at ~60us cold because
// each timed replay re-fetches ~50MB through a flushed cache at ~1TB/s.
// The converts stream that data at fill-rate and main re-reads it hot.

#define MOT_CAP     64
#define MOT_OVF_CAP 4096

using half8 = __attribute__((ext_vector_type(8))) _Float16;
using f32x4 = __attribute__((ext_vector_type(4))) float;

__global__ void mot_zero_kernel(int4* __restrict__ p, int n4) {
    const int i = blockIdx.x * 256 + (int)threadIdx.x;
    if (i < n4) p[i] = make_int4(0, 0, 0, 0);
}

// Pack user rows: out chunk c (of 64 per user) = halves [q*8,q*8+8) of row r,
// r = c>>2, q = c&3; rows 0-7 = attn, 8-15 = taste.
__global__ void mot_cvt_users_kernel(const float4* __restrict__ attn,
                                     const float4* __restrict__ taste,
                                     half8* __restrict__ outp, int nTot) {
    const int i = blockIdx.x * 256 + (int)threadIdx.x;   // over nUsers*64
    if (i >= nTot) return;
    const int u = i >> 6, c = i & 63;
    const int r = c >> 2, q = c & 3;
    const float4* src = (r < 8)
        ? attn  + (size_t)u * 64 + r * 8 + q * 2
        : taste + (size_t)u * 64 + (r - 8) * 8 + q * 2;
    const float4 a = src[0], b = src[1];
    half8 h;
    h[0] = (_Float16)a.x; h[1] = (_Float16)a.y;
    h[2] = (_Float16)a.z; h[3] = (_Float16)a.w;
    h[4] = (_Float16)b.x; h[5] = (_Float16)b.y;
    h[6] = (_Float16)b.z; h[7] = (_Float16)b.w;
    outp[i] = h;
}

// Pack movie rows: chunk c (of 4 per movie) = halves [q*8,q*8+8).
__global__ void mot_cvt_movies_kernel(const float4* __restrict__ movie,
                                      half8* __restrict__ outp, int nTot) {
    const int i = blockIdx.x * 256 + (int)threadIdx.x;   // over nMovies*4
    if (i >= nTot) return;
    const int v = i >> 2, q = i & 3;
    const float4* src = movie + (size_t)v * 8 + q * 2;
    const float4 a = src[0], b = src[1];
    half8 h;
    h[0] = (_Float16)a.x; h[1] = (_Float16)a.y;
    h[2] = (_Float16)a.z; h[3] = (_Float16)a.w;
    h[4] = (_Float16)b.x; h[5] = (_Float16)b.y;
    h[6] = (_Float16)b.z; h[7] = (_Float16)b.w;
    outp[i] = h;
}

// fp32 divergent-u per-edge score (overflow path only; rare).
__device__ __forceinline__ float mot_score_div(const float* __restrict__ Ar,
                                               const float* __restrict__ Tr,
                                               const float4* __restrict__ Ep) {
    float4 ek[8];
    #pragma unroll
    for (int k4 = 0; k4 < 8; ++k4) ek[k4] = Ep[k4];
    float num = 0.f, den = 0.f;
    #pragma unroll
    for (int m = 0; m < 8; ++m) {
        float l = 0.f, s = 0.f;
        #pragma unroll
        for (int k4 = 0; k4 < 8; ++k4) {
            const float4 a = *(const float4*)(Ar + m * 32 + k4 * 4);
            const float4 t = *(const float4*)(Tr + m * 32 + k4 * 4);
            const float4 e = ek[k4];
            l = fmaf(a.x, e.x, l); l = fmaf(a.y, e.y, l);
            l = fmaf(a.z, e.z, l); l = fmaf(a.w, e.w, l);
            s = fmaf(t.x, e.x, s); s = fmaf(t.y, e.y, s);
            s = fmaf(t.z, e.z, s); s = fmaf(t.w, e.w, s);
        }
        const float ex = __expf(l);
        den += ex;
        num = fmaf(ex, s, num);
    }
    return num / den;
}

__global__ void mot_scatter_kernel(const int4* __restrict__ edge2,
                                   int* __restrict__ cnt,
                                   int* __restrict__ ovfMeta,
                                   int* __restrict__ ovf,
                                   int2* __restrict__ sve,
                                   int nPairs, int nEdges) {
    const int i = blockIdx.x * 256 + (int)threadIdx.x;
    if (i < nPairs) {
        const int4 q = edge2[i];   // edges (q.x,q.y) eid=2i and (q.z,q.w) eid=2i+1
        int pos = atomicAdd(&cnt[q.x], 1);
        if (pos < MOT_CAP) sve[(size_t)q.x * MOT_CAP + pos] = make_int2(q.y, 2 * i);
        else { int o = atomicAdd(ovfMeta, 1); if (o < MOT_OVF_CAP) ovf[o] = 2 * i; }
        pos = atomicAdd(&cnt[q.z], 1);
        if (pos < MOT_CAP) sve[(size_t)q.z * MOT_CAP + pos] = make_int2(q.w, 2 * i + 1);
        else { int o = atomicAdd(ovfMeta, 1); if (o < MOT_OVF_CAP) ovf[o] = 2 * i + 1; }
    } else if (i == nPairs && (nEdges & 1)) {
        const int2 e = ((const int2*)edge2)[nEdges - 1];
        int pos = atomicAdd(&cnt[e.x], 1);
        if (pos < MOT_CAP) sve[(size_t)e.x * MOT_CAP + pos] = make_int2(e.y, nEdges - 1);
        else { int o = atomicAdd(ovfMeta, 1); if (o < MOT_OVF_CAP) ovf[o] = nEdges - 1; }
    }
}

__global__ __launch_bounds__(256, 4) void mot_mfma_packed_kernel(
    const int2* __restrict__ edge,
    const half8* __restrict__ pu,           // [NB][64] packed user half8
    const half8* __restrict__ pm,           // [NB][4] packed movie half8
    const float* __restrict__ taste_emb,    // fp32 (overflow path)
    const float* __restrict__ attn_emb,
    const float4* __restrict__ movie_emb,
    const float* __restrict__ user_bias,
    const float* __restrict__ movie_bias,
    const int* __restrict__ cnt,
    const int2* __restrict__ sve,
    const int* __restrict__ ovfMeta,
    const int* __restrict__ ovf,
    float* __restrict__ out,
    int nUsers, int nMovies, int mainBlocks)
{
    const int tid  = (int)threadIdx.x;
    const int lane = tid & 63;

    if ((int)blockIdx.x < mainBlocks) {
        const int u0 = ((int)blockIdx.x * 4 + (tid >> 6)) * 2;  // wave = 2 users
        const int u1 = u0 + 1;
        if (u0 >= nUsers) return;

        const int row = lane & 15;     // A row / C col / edge slot within tile
        const int kq  = lane >> 4;     // k-quarter 0..3

        int n0 = cnt[u0]; n0 = n0 > MOT_CAP ? MOT_CAP : n0;
        int n1 = (u1 < nUsers) ? cnt[u1] : 0; n1 = n1 > MOT_CAP ? MOT_CAP : n1;
        const half8 af0 = pu[(size_t)u0 * 64 + row * 4 + kq];
        const half8 af1 = pu[(size_t)u1 * 64 + row * 4 + kq];
        const float ub0 = user_bias[u0];
        const float ub1 = user_bias[u1];
        const int2* __restrict__ b0 = sve + (size_t)u0 * MOT_CAP;
        const int2* __restrict__ b1 = sve + (size_t)u1 * MOT_CAP;

        for (int t = 0; t < MOT_CAP; t += 16) {
            if (t >= n0 && t >= n1) break;          // wave-uniform

            // ---- load phase: both users' slots then movie chunks ----
            int2 ve0 = make_int2(0, 0), ve1 = make_int2(0, 0);
            const bool d0 = t < n0, d1 = t < n1;
            if (d0) ve0 = b0[t + row];
            if (d1) ve1 = b1[t + row];
            // Clamp garbage slots (beyond n, 0xAA poison) to movie 0.
            const int vx0 = ((unsigned)ve0.x < (unsigned)nMovies) ? ve0.x : 0;
            const int vx1 = ((unsigned)ve1.x < (unsigned)nMovies) ? ve1.x : 0;
            half8 bf0 = {}, bf1 = {};
            if (d0) bf0 = pm[(size_t)vx0 * 4 + kq];
            if (d1) bf1 = pm[(size_t)vx1 * 4 + kq];

            // ---- compute phase ----
            #pragma unroll
            for (int g = 0; g < 2; ++g) {
                const bool dg = g ? d1 : d0;
                if (!dg) continue;                  // wave-uniform
                const int   n  = g ? n1 : n0;
                const half8 af = g ? af1 : af0;
                const half8 bf = g ? bf1 : bf0;
                const int2  ve = g ? ve1 : ve0;
                const float ub = g ? ub1 : ub0;

                f32x4 c = {0.f, 0.f, 0.f, 0.f};
                c = __builtin_amdgcn_mfma_f32_16x16x32_f16(af, bf, c, 0, 0, 0);
                // c[j] = C[kq*4+j][col]: kq0=L0-3, kq1=L4-7, kq2=S0-3, kq3=S4-7.

                // xor32 swaps L-quarters with S-quarters.
                const float s0 = __shfl_xor(c[0], 32);
                const float s1 = __shfl_xor(c[1], 32);
                const float s2 = __shfl_xor(c[2], 32);
                const float s3 = __shfl_xor(c[3], 32);
                // Partial softmax over this quarter's 4 logits (lanes 0-31
                // meaningful). |logit| < ~0.05: unstabilized softmax exact.
                const float e0x = __expf(c[0]);
                const float e1x = __expf(c[1]);
                const float e2x = __expf(c[2]);
                const float e3x = __expf(c[3]);
                float den = e0x + e1x + e2x + e3x;
                float num = e0x * s0;
                num = fmaf(e1x, s1, num);
                num = fmaf(e2x, s2, num);
                num = fmaf(e3x, s3, num);
                // xor16 combines the two L-quarters' partials.
                den += __shfl_xor(den, 16);
                num += __shfl_xor(num, 16);

                if (kq == 0) {
                    const int ei = t + row;
                    if (ei < n)
                        out[ve.y] = num * __builtin_amdgcn_rcpf(den) + ub
                                    + movie_bias[ve.x];
                }
            }
        }
    } else {
        // Overflow edges (normally zero): fp32 divergent-u compute.
        int oc = ovfMeta[0];
        if (oc > MOT_OVF_CAP) oc = MOT_OVF_CAP;
        const int oi = ((int)blockIdx.x - mainBlocks) * 256 + tid;
        if (oi < oc) {
            const int eid = ovf[oi];
            const int2 ed = edge[eid];
            out[eid] = mot_score_div(attn_emb  + (size_t)ed.x * 256,
                                     taste_emb + (size_t)ed.x * 256,
                                     movie_emb + (size_t)ed.y * 8)
                       + user_bias[ed.x] + movie_bias[ed.y];
        }
    }
}

// ---- flat fallback (no scratch needed) ----
__global__ __launch_bounds__(256, 4) void mot_flat_kernel(
    const int2* __restrict__ edge,
    const float4* __restrict__ taste_emb,
    const float4* __restrict__ attn_emb,
    const float4* __restrict__ movie_emb,
    const float* __restrict__ user_bias,
    const float* __restrict__ movie_bias,
    float* __restrict__ out,
    int nEdges)
{
    const int tid  = blockIdx.x * 256 + (int)threadIdx.x;
    const int eid  = tid >> 5;
    const int s    = tid & 31;
    if (eid >= nEdges) return;
    const int2 ed = edge[eid];
    const int u = ed.x, v = ed.y;
    const float4* Ap = attn_emb  + (size_t)u * 64;
    const float4* Tp = taste_emb + (size_t)u * 64;
    const float4* Ep = movie_emb + (size_t)v * 8;
    const float4 a0 = Ap[2 * s], a1 = Ap[2 * s + 1];
    const float4 t0 = Tp[2 * s], t1 = Tp[2 * s + 1];
    const int c = s & 3;
    const float4 e0 = Ep[2 * c], e1 = Ep[2 * c + 1];
    float lp = a0.x*e0.x + a0.y*e0.y + a0.z*e0.z + a0.w*e0.w
             + a1.x*e1.x + a1.y*e1.y + a1.z*e1.z + a1.w*e1.w;
    float sp = t0.x*e0.x + t0.y*e0.y + t0.z*e0.z + t0.w*e0.w
             + t1.x*e1.x + t1.y*e1.y + t1.z*e1.z + t1.w*e1.w;
    lp += __shfl_xor(lp, 1); lp += __shfl_xor(lp, 2);
    sp += __shfl_xor(sp, 1); sp += __shfl_xor(sp, 2);
    const float ex = __expf(lp);
    float den = ex, num = ex * sp;
    den += __shfl_xor(den, 4);  num += __shfl_xor(num, 4);
    den += __shfl_xor(den, 8);  num += __shfl_xor(num, 8);
    den += __shfl_xor(den, 16); num += __shfl_xor(num, 16);
    if (s == 0) out[eid] = num / den + user_bias[u] + movie_bias[v];
}

extern "C" void kernel_launch(void* const* d_in, const int* in_sizes, int n_in,
                              void* d_out, int out_size, void* d_ws, size_t ws_size,
                              hipStream_t stream) {
    const int2*   edge       = (const int2*)d_in[0];
    const float*  taste_emb  = (const float*)d_in[1];
    const float*  attn_emb   = (const float*)d_in[2];
    const float*  movie_emb  = (const float*)d_in[3];
    const float*  user_bias  = (const float*)d_in[4];
    const float*  movie_bias = (const float*)d_in[5];
    float*        out        = (float*)d_out;

    const int nEdges = in_sizes[0] / 2;     // edge is [B,2] int32
    const int NB     = in_sizes[3] / 32;    // id bound (20000)

    auto align256 = [](size_t x) { return (x + 255) & ~(size_t)255; };
    char* ws = (char*)d_ws;

    const size_t o_cnt  = 0;
    const size_t o_meta = align256((size_t)NB * 4);
    const size_t o_ovf  = o_meta + 256;
    const size_t o_sve  = align256(o_ovf + (size_t)MOT_OVF_CAP * 4);
    const size_t o_pu   = align256(o_sve + (size_t)NB * MOT_CAP * 8);
    const size_t o_pm   = align256(o_pu + (size_t)NB * 1024);
    const size_t need   = o_pm + (size_t)NB * 64;

    if (ws_size < need) {
        const int blocks = (nEdges * 32 + 255) / 256;
        mot_flat_kernel<<<blocks, 256, 0, stream>>>(
            edge, (const float4*)taste_emb, (const float4*)attn_emb,
            (const float4*)movie_emb, user_bias, movie_bias, out, nEdges);
        return;
    }

    int*   cnt     = (int*)(ws + o_cnt);
    int*   ovfMeta = (int*)(ws + o_meta);
    int*   ovf     = (int*)(ws + o_ovf);
    int2*  sve     = (int2*)(ws + o_sve);
    half8* pu      = (half8*)(ws + o_pu);
    half8* pm      = (half8*)(ws + o_pm);

    const int n4 = (int)(o_ovf / 16);
    mot_zero_kernel<<<(n4 + 255) / 256, 256, 0, stream>>>((int4*)ws, n4);

    const int nuChunks = NB * 64;
    mot_cvt_users_kernel<<<(nuChunks + 255) / 256, 256, 0, stream>>>(
        (const float4*)attn_emb, (const float4*)taste_emb, pu, nuChunks);
    const int nmChunks = NB * 4;
    mot_cvt_movies_kernel<<<(nmChunks + 255) / 256, 256, 0, stream>>>(
        (const float4*)movie_emb, pm, nmChunks);

    const int nPairs  = nEdges / 2;
    const int sblocks = (nPairs + 1 + 255) / 256;
    mot_scatter_kernel<<<sblocks, 256, 0, stream>>>(
        (const int4*)edge, cnt, ovfMeta, ovf, sve, nPairs, nEdges);

    const int mainBlocks = (NB + 7) / 8;        // 2 users/wave, 4 waves/block
    const int ovfBlocks  = MOT_OVF_CAP / 256;
    mot_mfma_packed_kernel<<<mainBlocks + ovfBlocks, 256, 0, stream>>>(
        edge, pu, pm, taste_emb, attn_emb, (const float4*)movie_emb,
        user_bias, movie_bias, cnt, sve, ovfMeta, ovf, out, NB, NB, mainBlocks);
}

// Round 14
// 64.828 us; speedup vs baseline: 1.0812x; 1.0812x over previous
//
#include <hip/hip_runtime.h>

// Mixture-of-Tastes forward — (user,tile)-parallel MFMA main for max cold-MLP:
//   zero:    cnt[NB]+ovfMeta = 0
//   scatter: fixed-cap user buckets (cap=64) + overflow list
//   main:    ONE WAVE PER 16-EDGE TILE (4 waves/user, 80K waves). Each wave
//            issues its A-frag (2 ld/lane), bucket slot, and movie-row loads
//            immediately and independently -> R1-level memory concurrency
//            (64K chains @ 3.65TB/s proven) on R9's minimal ~70MB volume.
//            R4-R13 showed per-user waves serialize the cold gather at ~1TB/s;
//            every timed replay is cache-cold (reset()'s 400MB ws-poison fill
//            flushes L3 between replays).
// Per-edge output is order-independent -> deterministic despite atomic scatter.

#define MOT_CAP     64
#define MOT_OVF_CAP 4096

using half8 = __attribute__((ext_vector_type(8))) _Float16;
using f32x4 = __attribute__((ext_vector_type(4))) float;

__global__ void mot_zero_kernel(int4* __restrict__ p, int n4) {
    const int i = blockIdx.x * 256 + (int)threadIdx.x;
    if (i < n4) p[i] = make_int4(0, 0, 0, 0);
}

// fp32 divergent-u per-edge score (overflow path only; rare).
__device__ __forceinline__ float mot_score_div(const float* __restrict__ Ar,
                                               const float* __restrict__ Tr,
                                               const float4* __restrict__ Ep) {
    float4 ek[8];
    #pragma unroll
    for (int k4 = 0; k4 < 8; ++k4) ek[k4] = Ep[k4];
    float num = 0.f, den = 0.f;
    #pragma unroll
    for (int m = 0; m < 8; ++m) {
        float l = 0.f, s = 0.f;
        #pragma unroll
        for (int k4 = 0; k4 < 8; ++k4) {
            const float4 a = *(const float4*)(Ar + m * 32 + k4 * 4);
            const float4 t = *(const float4*)(Tr + m * 32 + k4 * 4);
            const float4 e = ek[k4];
            l = fmaf(a.x, e.x, l); l = fmaf(a.y, e.y, l);
            l = fmaf(a.z, e.z, l); l = fmaf(a.w, e.w, l);
            s = fmaf(t.x, e.x, s); s = fmaf(t.y, e.y, s);
            s = fmaf(t.z, e.z, s); s = fmaf(t.w, e.w, s);
        }
        const float ex = __expf(l);
        den += ex;
        num = fmaf(ex, s, num);
    }
    return num / den;
}

__global__ void mot_scatter_kernel(const int4* __restrict__ edge2,
                                   int* __restrict__ cnt,
                                   int* __restrict__ ovfMeta,
                                   int* __restrict__ ovf,
                                   int2* __restrict__ sve,
                                   int nPairs, int nEdges) {
    const int i = blockIdx.x * 256 + (int)threadIdx.x;
    if (i < nPairs) {
        const int4 q = edge2[i];   // edges (q.x,q.y) eid=2i and (q.z,q.w) eid=2i+1
        int pos = atomicAdd(&cnt[q.x], 1);
        if (pos < MOT_CAP) sve[(size_t)q.x * MOT_CAP + pos] = make_int2(q.y, 2 * i);
        else { int o = atomicAdd(ovfMeta, 1); if (o < MOT_OVF_CAP) ovf[o] = 2 * i; }
        pos = atomicAdd(&cnt[q.z], 1);
        if (pos < MOT_CAP) sve[(size_t)q.z * MOT_CAP + pos] = make_int2(q.w, 2 * i + 1);
        else { int o = atomicAdd(ovfMeta, 1); if (o < MOT_OVF_CAP) ovf[o] = 2 * i + 1; }
    } else if (i == nPairs && (nEdges & 1)) {
        const int2 e = ((const int2*)edge2)[nEdges - 1];
        int pos = atomicAdd(&cnt[e.x], 1);
        if (pos < MOT_CAP) sve[(size_t)e.x * MOT_CAP + pos] = make_int2(e.y, nEdges - 1);
        else { int o = atomicAdd(ovfMeta, 1); if (o < MOT_OVF_CAP) ovf[o] = nEdges - 1; }
    }
}

__global__ __launch_bounds__(256, 8) void mot_tile_kernel(
    const int2* __restrict__ edge,
    const float* __restrict__ taste_emb,    // [N_USERS][256]
    const float* __restrict__ attn_emb,     // [N_USERS][256]
    const float4* __restrict__ movie_emb,   // [N_MOVIES][8] float4
    const float* __restrict__ user_bias,
    const float* __restrict__ movie_bias,
    const int* __restrict__ cnt,
    const int2* __restrict__ sve,
    const int* __restrict__ ovfMeta,
    const int* __restrict__ ovf,
    float* __restrict__ out,
    int nUsers, int nMovies, int mainBlocks)
{
    const int tid  = (int)threadIdx.x;
    const int lane = tid & 63;

    if ((int)blockIdx.x < mainBlocks) {
        const int w = (int)blockIdx.x * 4 + (tid >> 6);   // wave = (user, tile)
        const int u = w >> 2;
        const int T = w & 3;
        if (u >= nUsers) return;

        const int row = lane & 15;     // A row / C col / edge slot within tile
        const int kq  = lane >> 4;     // k-quarter 0..3
        const int k0  = kq * 8;
        const int t   = T * 16;        // tile base within bucket

        // Issue ALL independent loads up front:
        // (1) bucket slot (d_ws; needed for movie row — the only chain)
        const int2 ve = sve[(size_t)u * MOT_CAP + t + row];
        // (2) count + bias (scalar)
        int n = cnt[u]; n = n > MOT_CAP ? MOT_CAP : n;
        // (3) A-frag from d_in: rows 0-7 attn, 8-15 taste; 8 floats @ k0.
        const float* rowp = (row < 8)
            ? attn_emb  + (size_t)u * 256 + row * 32 + k0
            : taste_emb + (size_t)u * 256 + (row - 8) * 32 + k0;
        const float4 r0 = *(const float4*)rowp;
        const float4 r1 = *(const float4*)(rowp + 4);

        if (t >= n) return;                 // wave-uniform exit (tile empty)
        const float ub = user_bias[u];

        // Movie row (depends only on the bucket slot). Clamp garbage slots.
        const int vx = ((unsigned)ve.x < (unsigned)nMovies) ? ve.x : 0;
        const float4* __restrict__ Ep = movie_emb + (size_t)vx * 8;
        const float4 e0 = Ep[kq * 2], e1 = Ep[kq * 2 + 1];

        half8 af, bf;
        af[0] = (_Float16)r0.x; af[1] = (_Float16)r0.y;
        af[2] = (_Float16)r0.z; af[3] = (_Float16)r0.w;
        af[4] = (_Float16)r1.x; af[5] = (_Float16)r1.y;
        af[6] = (_Float16)r1.z; af[7] = (_Float16)r1.w;
        bf[0] = (_Float16)e0.x; bf[1] = (_Float16)e0.y;
        bf[2] = (_Float16)e0.z; bf[3] = (_Float16)e0.w;
        bf[4] = (_Float16)e1.x; bf[5] = (_Float16)e1.y;
        bf[6] = (_Float16)e1.z; bf[7] = (_Float16)e1.w;

        f32x4 c = {0.f, 0.f, 0.f, 0.f};
        c = __builtin_amdgcn_mfma_f32_16x16x32_f16(af, bf, c, 0, 0, 0);
        // c[j] = C[kq*4+j][col]: kq0=L0-3, kq1=L4-7, kq2=S0-3, kq3=S4-7.

        // xor32 swaps L-quarters with S-quarters.
        const float s0 = __shfl_xor(c[0], 32);
        const float s1 = __shfl_xor(c[1], 32);
        const float s2 = __shfl_xor(c[2], 32);
        const float s3 = __shfl_xor(c[3], 32);
        // Partial softmax over this quarter's 4 logits (lanes 0-31 compute).
        // |logit| < ~0.05 (inputs scaled 1/K): unstabilized softmax is exact.
        const float e0x = __expf(c[0]);
        const float e1x = __expf(c[1]);
        const float e2x = __expf(c[2]);
        const float e3x = __expf(c[3]);
        float den = e0x + e1x + e2x + e3x;
        float num = e0x * s0;
        num = fmaf(e1x, s1, num);
        num = fmaf(e2x, s2, num);
        num = fmaf(e3x, s3, num);
        // xor16 combines the two L-quarter partials.
        den += __shfl_xor(den, 16);
        num += __shfl_xor(num, 16);

        if (kq == 0) {
            const int ei = t + row;
            if (ei < n)
                out[ve.y] = num * __builtin_amdgcn_rcpf(den) + ub + movie_bias[ve.x];
        }
    } else {
        // Overflow edges (normally zero): fp32 divergent-u compute.
        int oc = ovfMeta[0];
        if (oc > MOT_OVF_CAP) oc = MOT_OVF_CAP;
        const int oi = ((int)blockIdx.x - mainBlocks) * 256 + tid;
        if (oi < oc) {
            const int eid = ovf[oi];
            const int2 ed = edge[eid];
            out[eid] = mot_score_div(attn_emb  + (size_t)ed.x * 256,
                                     taste_emb + (size_t)ed.x * 256,
                                     movie_emb + (size_t)ed.y * 8)
                       + user_bias[ed.x] + movie_bias[ed.y];
        }
    }
}

// ---- flat fallback (no scratch needed) ----
__global__ __launch_bounds__(256, 4) void mot_flat_kernel(
    const int2* __restrict__ edge,
    const float4* __restrict__ taste_emb,
    const float4* __restrict__ attn_emb,
    const float4* __restrict__ movie_emb,
    const float* __restrict__ user_bias,
    const float* __restrict__ movie_bias,
    float* __restrict__ out,
    int nEdges)
{
    const int tid  = blockIdx.x * 256 + (int)threadIdx.x;
    const int eid  = tid >> 5;
    const int s    = tid & 31;
    if (eid >= nEdges) return;
    const int2 ed = edge[eid];
    const int u = ed.x, v = ed.y;
    const float4* Ap = attn_emb  + (size_t)u * 64;
    const float4* Tp = taste_emb + (size_t)u * 64;
    const float4* Ep = movie_emb + (size_t)v * 8;
    const float4 a0 = Ap[2 * s], a1 = Ap[2 * s + 1];
    const float4 t0 = Tp[2 * s], t1 = Tp[2 * s + 1];
    const int c = s & 3;
    const float4 e0 = Ep[2 * c], e1 = Ep[2 * c + 1];
    float lp = a0.x*e0.x + a0.y*e0.y + a0.z*e0.z + a0.w*e0.w
             + a1.x*e1.x + a1.y*e1.y + a1.z*e1.z + a1.w*e1.w;
    float sp = t0.x*e0.x + t0.y*e0.y + t0.z*e0.z + t0.w*e0.w
             + t1.x*e1.x + t1.y*e1.y + t1.z*e1.z + t1.w*e1.w;
    lp += __shfl_xor(lp, 1); lp += __shfl_xor(lp, 2);
    sp += __shfl_xor(sp, 1); sp += __shfl_xor(sp, 2);
    const float ex = __expf(lp);
    float den = ex, num = ex * sp;
    den += __shfl_xor(den, 4);  num += __shfl_xor(num, 4);
    den += __shfl_xor(den, 8);  num += __shfl_xor(num, 8);
    den += __shfl_xor(den, 16); num += __shfl_xor(num, 16);
    if (s == 0) out[eid] = num / den + user_bias[u] + movie_bias[v];
}

extern "C" void kernel_launch(void* const* d_in, const int* in_sizes, int n_in,
                              void* d_out, int out_size, void* d_ws, size_t ws_size,
                              hipStream_t stream) {
    const int2*   edge       = (const int2*)d_in[0];
    const float*  taste_emb  = (const float*)d_in[1];
    const float*  attn_emb   = (const float*)d_in[2];
    const float*  movie_emb  = (const float*)d_in[3];
    const float*  user_bias  = (const float*)d_in[4];
    const float*  movie_bias = (const float*)d_in[5];
    float*        out        = (float*)d_out;

    const int nEdges = in_sizes[0] / 2;     // edge is [B,2] int32
    const int NB     = in_sizes[3] / 32;    // id bound (20000)

    auto align256 = [](size_t x) { return (x + 255) & ~(size_t)255; };
    char* ws = (char*)d_ws;

    const size_t o_cnt  = 0;
    const size_t o_meta = align256((size_t)NB * 4);
    const size_t o_ovf  = o_meta + 256;
    const size_t o_sve  = align256(o_ovf + (size_t)MOT_OVF_CAP * 4);
    const size_t need   = o_sve + (size_t)NB * MOT_CAP * 8;

    if (ws_size < need) {
        const int blocks = (nEdges * 32 + 255) / 256;
        mot_flat_kernel<<<blocks, 256, 0, stream>>>(
            edge, (const float4*)taste_emb, (const float4*)attn_emb,
            (const float4*)movie_emb, user_bias, movie_bias, out, nEdges);
        return;
    }

    int*  cnt     = (int*)(ws + o_cnt);
    int*  ovfMeta = (int*)(ws + o_meta);
    int*  ovf     = (int*)(ws + o_ovf);
    int2* sve     = (int2*)(ws + o_sve);

    const int n4 = (int)(o_ovf / 16);
    mot_zero_kernel<<<(n4 + 255) / 256, 256, 0, stream>>>((int4*)ws, n4);

    const int nPairs  = nEdges / 2;
    const int sblocks = (nPairs + 1 + 255) / 256;
    mot_scatter_kernel<<<sblocks, 256, 0, stream>>>(
        (const int4*)edge, cnt, ovfMeta, ovf, sve, nPairs, nEdges);

    const int mainBlocks = NB;                  // 4 (user,tile) waves per block
    const int ovfBlocks  = MOT_OVF_CAP / 256;
    mot_tile_kernel<<<mainBlocks + ovfBlocks, 256, 0, stream>>>(
        edge, taste_emb, attn_emb, (const float4*)movie_emb,
        user_bias, movie_bias, cnt, sve, ovfMeta, ovf, out, NB, NB, mainBlocks);
}